// Round 1
// baseline (660.683 us; speedup 1.0000x reference)
//
#include <hip/hip_runtime.h>

#define NN 50000
#define NE 800000

typedef __attribute__((ext_vector_type(8))) short bf16x8;
typedef __attribute__((ext_vector_type(4))) float f32x4;

__device__ __forceinline__ short f2bf(float f) {
    union { float f; unsigned u; } v; v.f = f;
    return (short)((v.u + 0x7fffu + ((v.u >> 16) & 1u)) >> 16);
}

__device__ __forceinline__ bf16x8 cvt8(const float* __restrict__ p) {
    const f32x4 a = *(const f32x4*)p;
    const f32x4 b = *(const f32x4*)(p + 4);
    bf16x8 r;
#pragma unroll
    for (int j = 0; j < 4; ++j) { r[j] = f2bf(a[j]); r[j + 4] = f2bf(b[j]); }
    return r;
}

// Stage W (KROWS x 128 row-major fp32) into LDS as swizzled bf16 MFMA B-fragments.
// Frag f = s*8 + t covers k in [32s,32s+32), n in [16t,16t+16).
// Lane l of frag f holds B[32s + (l>>4)*8 + j][16t + (l&15)], j=0..7, at lds[(f*64+l)*8].
template<int KROWS, int NTHREADS>
__device__ __forceinline__ void stage_w(const float* __restrict__ W, short* lds, int tid) {
    constexpr int NSLOT = (KROWS / 32) * 8 * 64;
#pragma unroll 1
    for (int slot = tid; slot < NSLOT; slot += NTHREADS) {
        const int f = slot >> 6, l = slot & 63;
        const int s = f >> 3, t = f & 7;
        const int k0 = 32 * s + ((l >> 4) << 3);
        const int n = 16 * t + (l & 15);
        bf16x8 v;
#pragma unroll
        for (int j = 0; j < 8; ++j) v[j] = f2bf(W[(k0 + j) * 128 + n]);
        *(bf16x8*)(lds + slot * 8) = v;
    }
}

// P = h @ Wm1[0:128,:], Q = h @ Wm1[128:256,:]
__global__ __launch_bounds__(256) void node_pq_kernel(
    const float* __restrict__ h, const float* __restrict__ Wm1,
    float* __restrict__ P, float* __restrict__ Q)
{
    __shared__ short sWa[16384];
    __shared__ short sWb[16384];
    const int tid = threadIdx.x;
    stage_w<128, 256>(Wm1, sWa, tid);
    stage_w<128, 256>(Wm1 + 128 * 128, sWb, tid);
    __syncthreads();
    const int wave = tid >> 6, lane = tid & 63;
    const int q = lane >> 4, col = lane & 15;
    for (int tile = blockIdx.x * 4 + wave; tile < NN / 16; tile += gridDim.x * 4) {
        const int r0 = tile * 16;
        f32x4 aP[8], aQ[8];
#pragma unroll
        for (int t = 0; t < 8; ++t) { aP[t] = {0.f, 0.f, 0.f, 0.f}; aQ[t] = {0.f, 0.f, 0.f, 0.f}; }
#pragma unroll
        for (int s = 0; s < 4; ++s) {
            const bf16x8 ah = cvt8(&h[(r0 + col) * 128 + s * 32 + q * 8]);
#pragma unroll
            for (int t = 0; t < 8; ++t) {
                const bf16x8 ba = *(const bf16x8*)(sWa + ((s * 8 + t) * 64 + lane) * 8);
                const bf16x8 bb = *(const bf16x8*)(sWb + ((s * 8 + t) * 64 + lane) * 8);
                aP[t] = __builtin_amdgcn_mfma_f32_16x16x32_bf16(ah, ba, aP[t], 0, 0, 0);
                aQ[t] = __builtin_amdgcn_mfma_f32_16x16x32_bf16(ah, bb, aQ[t], 0, 0, 0);
            }
        }
#pragma unroll
        for (int t = 0; t < 8; ++t)
#pragma unroll
            for (int r = 0; r < 4; ++r) {
                const int o = (r0 + q * 4 + r) * 128 + t * 16 + col;
                P[o] = aP[t][r];
                Q[o] = aQ[t][r];
            }
    }
}

// Per 16-edge tile: pre1 = P[src]+Q[dst]+bm1 + ea@W1c; x=relu; msg=relu(x@Wm2+bm2); atomic scatter.
__global__ __launch_bounds__(512) void edge_kernel(
    const float* __restrict__ P, const float* __restrict__ Q,
    const float* __restrict__ ea, const float* __restrict__ W1c,
    const float* __restrict__ bm1, const float* __restrict__ Wm2,
    const float* __restrict__ bm2, const int* __restrict__ eidx,
    float* __restrict__ agg)
{
    __shared__ short sW2[16384];   // 32 KB
    __shared__ short sW1c[4096];   // 8 KB
    __shared__ float sb1[128];
    __shared__ float sb2[128];
    __shared__ short sX[8][16 * 136];  // per-wave X buffer, padded stride
    const int tid = threadIdx.x;
    stage_w<128, 512>(Wm2, sW2, tid);
    stage_w<32, 512>(W1c, sW1c, tid);
    if (tid < 128) { sb1[tid] = bm1[tid]; sb2[tid] = bm2[tid]; }
    __syncthreads();
    const int wave = tid >> 6, lane = tid & 63;
    const int q = lane >> 4, col = lane & 15;
    short* myX = &sX[wave][0];
    for (int tile = blockIdx.x * 8 + wave; tile < NE / 16; tile += gridDim.x * 8) {
        const int e0 = tile * 16;
        int sr[4], dr[4];
#pragma unroll
        for (int r = 0; r < 4; ++r) {
            const int e = e0 + q * 4 + r;
            sr[r] = eidx[e];
            dr[r] = eidx[NE + e];
        }
        // layer-1 accumulator init: gathered P[src] + Q[dst] + bias (C-layout)
        f32x4 acc1[8];
#pragma unroll
        for (int t = 0; t < 8; ++t) {
            const float b = sb1[t * 16 + col];
#pragma unroll
            for (int r = 0; r < 4; ++r)
                acc1[t][r] = P[sr[r] * 128 + t * 16 + col] + Q[dr[r] * 128 + t * 16 + col] + b;
        }
        // + ea @ W1c (one K=32 MFMA step)
        const bf16x8 aea = cvt8(&ea[(e0 + col) * 32 + q * 8]);
#pragma unroll
        for (int t = 0; t < 8; ++t) {
            const bf16x8 bw = *(const bf16x8*)(sW1c + (t * 64 + lane) * 8);
            acc1[t] = __builtin_amdgcn_mfma_f32_16x16x32_bf16(aea, bw, acc1[t], 0, 0, 0);
        }
        // relu -> bf16 -> LDS (C-layout write)
#pragma unroll
        for (int t = 0; t < 8; ++t)
#pragma unroll
            for (int r = 0; r < 4; ++r) {
                const float x = acc1[t][r];
                myX[(q * 4 + r) * 136 + t * 16 + col] = f2bf(x > 0.f ? x : 0.f);
            }
        // layer 2: msg = relu(X @ Wm2 + bm2)
        f32x4 acc2[8];
#pragma unroll
        for (int t = 0; t < 8; ++t) {
            const float b = sb2[t * 16 + col];
            acc2[t] = {b, b, b, b};
        }
#pragma unroll
        for (int s = 0; s < 4; ++s) {
            const bf16x8 ax = *(const bf16x8*)(myX + col * 136 + s * 32 + q * 8);
#pragma unroll
            for (int t = 0; t < 8; ++t) {
                const bf16x8 bw = *(const bf16x8*)(sW2 + ((s * 8 + t) * 64 + lane) * 8);
                acc2[t] = __builtin_amdgcn_mfma_f32_16x16x32_bf16(ax, bw, acc2[t], 0, 0, 0);
            }
        }
        // relu + scatter-add (skip zeros: ~half the atomics)
#pragma unroll
        for (int t = 0; t < 8; ++t)
#pragma unroll
            for (int r = 0; r < 4; ++r) {
                const float m = acc2[t][r];
                if (m > 0.f)
                    unsafeAtomicAdd(&agg[dr[r] * 128 + t * 16 + col], m);
            }
    }
}

// h_new = h + Wu2^T relu(Wu1^T concat(h,agg) + bu1) + bu2
__global__ __launch_bounds__(512) void update_kernel(
    const float* __restrict__ h, const float* __restrict__ agg,
    const float* __restrict__ Wu1, const float* __restrict__ bu1,
    const float* __restrict__ Wu2, const float* __restrict__ bu2,
    float* __restrict__ out)
{
    __shared__ short sWa[16384];
    __shared__ short sWb[16384];
    __shared__ short sW2[16384];
    __shared__ float sb1[128];
    __shared__ float sb2[128];
    __shared__ short sX[8][16 * 136];
    const int tid = threadIdx.x;
    stage_w<128, 512>(Wu1, sWa, tid);
    stage_w<128, 512>(Wu1 + 128 * 128, sWb, tid);
    stage_w<128, 512>(Wu2, sW2, tid);
    if (tid < 128) { sb1[tid] = bu1[tid]; sb2[tid] = bu2[tid]; }
    __syncthreads();
    const int wave = tid >> 6, lane = tid & 63;
    const int q = lane >> 4, col = lane & 15;
    short* myX = &sX[wave][0];
    for (int tile = blockIdx.x * 8 + wave; tile < NN / 16; tile += gridDim.x * 8) {
        const int r0 = tile * 16;
        f32x4 acc1[8];
#pragma unroll
        for (int t = 0; t < 8; ++t) {
            const float b = sb1[t * 16 + col];
            acc1[t] = {b, b, b, b};
        }
#pragma unroll
        for (int s = 0; s < 4; ++s) {
            const bf16x8 ahh = cvt8(&h[(r0 + col) * 128 + s * 32 + q * 8]);
            const bf16x8 aag = cvt8(&agg[(r0 + col) * 128 + s * 32 + q * 8]);
#pragma unroll
            for (int t = 0; t < 8; ++t) {
                const bf16x8 ba = *(const bf16x8*)(sWa + ((s * 8 + t) * 64 + lane) * 8);
                const bf16x8 bb = *(const bf16x8*)(sWb + ((s * 8 + t) * 64 + lane) * 8);
                acc1[t] = __builtin_amdgcn_mfma_f32_16x16x32_bf16(ahh, ba, acc1[t], 0, 0, 0);
                acc1[t] = __builtin_amdgcn_mfma_f32_16x16x32_bf16(aag, bb, acc1[t], 0, 0, 0);
            }
        }
#pragma unroll
        for (int t = 0; t < 8; ++t)
#pragma unroll
            for (int r = 0; r < 4; ++r) {
                const float x = acc1[t][r];
                myX[(q * 4 + r) * 136 + t * 16 + col] = f2bf(x > 0.f ? x : 0.f);
            }
        // acc2 init = bu2 + residual h (fp32)
        f32x4 acc2[8];
#pragma unroll
        for (int t = 0; t < 8; ++t) {
            const float b = sb2[t * 16 + col];
#pragma unroll
            for (int r = 0; r < 4; ++r)
                acc2[t][r] = b + h[(r0 + q * 4 + r) * 128 + t * 16 + col];
        }
#pragma unroll
        for (int s = 0; s < 4; ++s) {
            const bf16x8 ax = *(const bf16x8*)(myX + col * 136 + s * 32 + q * 8);
#pragma unroll
            for (int t = 0; t < 8; ++t) {
                const bf16x8 bw = *(const bf16x8*)(sW2 + ((s * 8 + t) * 64 + lane) * 8);
                acc2[t] = __builtin_amdgcn_mfma_f32_16x16x32_bf16(ax, bw, acc2[t], 0, 0, 0);
            }
        }
#pragma unroll
        for (int t = 0; t < 8; ++t)
#pragma unroll
            for (int r = 0; r < 4; ++r)
                out[(r0 + q * 4 + r) * 128 + t * 16 + col] = acc2[t][r];
    }
}

extern "C" void kernel_launch(void* const* d_in, const int* in_sizes, int n_in,
                              void* d_out, int out_size, void* d_ws, size_t ws_size,
                              hipStream_t stream) {
    const float* h   = (const float*)d_in[0];
    const float* ea  = (const float*)d_in[1];
    const float* Wm1 = (const float*)d_in[2];
    const float* bm1 = (const float*)d_in[3];
    const float* Wm2 = (const float*)d_in[4];
    const float* bm2 = (const float*)d_in[5];
    const float* Wu1 = (const float*)d_in[6];
    const float* bu1 = (const float*)d_in[7];
    const float* Wu2 = (const float*)d_in[8];
    const float* bu2 = (const float*)d_in[9];
    const int* eidx  = (const int*)d_in[10];
    float* out = (float*)d_out;

    float* P   = (float*)d_ws;        // NN*128
    float* Q   = P + NN * 128;        // NN*128
    float* agg = Q + NN * 128;        // NN*128

    hipMemsetAsync(agg, 0, (size_t)NN * 128 * sizeof(float), stream);
    node_pq_kernel<<<512, 256, 0, stream>>>(h, Wm1, P, Q);
    edge_kernel<<<512, 512, 0, stream>>>(P, Q, ea, Wm1 + 256 * 128, bm1, Wm2, bm2, eidx, agg);
    update_kernel<<<256, 512, 0, stream>>>(h, agg, Wu1, bu1, Wu2, bu2, out);
}